// Round 8
// baseline (163.202 us; speedup 1.0000x reference)
//
#include <hip/hip_runtime.h>
#include <math.h>

#define BB 4
#define NSZ 2048
#define FDIM 128
#define ODIM 32
#define HH 8

typedef short short8 __attribute__((ext_vector_type(8)));
typedef float f32x4 __attribute__((ext_vector_type(4)));

// workspace layout (float units)
#define WS_EAP  0                 // float[B*H*N]  R_i = EA2/EA  = 65536 floats
#define WS_EBP  131072            // EB[B*H*N] + EB2[B*H*N]     = 131072 floats (SoA)
#define WS_ADJB 262144            // u32[B*N*64]                = 524288 words
#define WS_WHF  786432            // bf16 Wh B-frags            = 1048576 floats (4MB)
// whf: int4[((b*H+h)*64 + jt)*2 + ot][64 lanes]

// round-to-nearest-even float -> bf16, result in TOP 16 bits
__device__ __forceinline__ unsigned bfbits(float f) {
    unsigned u = __builtin_bit_cast(unsigned, f);
    return u + 0x7fffu + ((u >> 16) & 1u);
}
// dword = (bf16(b) << 16) | bf16(a)
__device__ __forceinline__ unsigned bfpack(float a, float b) {
    return __builtin_amdgcn_perm(bfbits(b), bfbits(a), 0x07060302);
}

// ---------------------------------------------------------------------------
// Fused prep. Blocks [0,1024): MFMA projection for one (b,h,64 n-rows) --
// placed FIRST in the grid (long pole, overlaps the adj stream).
// Blocks [1024,1024+4096): adj bitmask pack, grid-strided 4 chunks/block.
// ---------------------------------------------------------------------------
__global__ __launch_bounds__(256) void k_prep(const float* __restrict__ x,
                                              const float* __restrict__ adj,
                                              const float* __restrict__ W,
                                              const float* __restrict__ a_src,
                                              const float* __restrict__ a_dst,
                                              unsigned* __restrict__ adjb,
                                              int4* __restrict__ whf,
                                              float* __restrict__ eap,
                                              float* __restrict__ ebe,
                                              float* __restrict__ ebe2) {
    __shared__ float wsl[FDIM * 33];          // W[h] staged, row-padded (k*33+o)
    __shared__ unsigned short wlds[64][33];   // bf16 Wh tile [local n][o], +1 pad
    int t = threadIdx.x;

    if (blockIdx.x >= 1024) {
        // ---------------- adj bitmask part (4 chunks, MLP x4) ----------------
        int bid = blockIdx.x - 1024;
#pragma unroll
        for (int it = 0; it < 4; it++) {
            int g = (it * 4096 + bid) * 256 + t;
            int l = g & 7;
            int word = g >> 3;
            int wk = word & 63;
            int row = word >> 6;
            int i = row & (NSZ - 1);
            const float4 v = *(const float4*)&adj[(size_t)row * NSZ + wk * 32 + l * 4];
            unsigned m = 0;
            if (v.x > 0.f) m |= 1u << (l * 4 + 0);
            if (v.y > 0.f) m |= 1u << (l * 4 + 1);
            if (v.z > 0.f) m |= 1u << (l * 4 + 2);
            if (v.w > 0.f) m |= 1u << (l * 4 + 3);
            m |= (unsigned)__shfl_xor((int)m, 1);
            m |= (unsigned)__shfl_xor((int)m, 2);
            m |= (unsigned)__shfl_xor((int)m, 4);
            if (l == 0) {
                int jb = i - wk * 32;
                if (jb >= 0 && jb < 32) m |= 1u << jb;  // self-loop
                adjb[word] = m;
            }
        }
        return;
    }

    // ---------------- projection part ----------------
    int bidx = blockIdx.x;                      // [0,1024): b(2) h(3) nt(5)
    int b = bidx >> 8;
    int h = (bidx >> 5) & 7;
    int nt = bidx & 31;
    int n0 = nt * 64;
    int w = t >> 6, lane = t & 63;
    int col = lane & 15, quad = lane >> 4;

    // stage W[h] (4096 floats) coalesced into padded LDS
#pragma unroll
    for (int m = 0; m < 16; m++) {
        int idx = t + m * 256;
        wsl[(idx >> 5) * 33 + (idx & 31)] = W[(size_t)h * (FDIM * ODIM) + idx];
    }

    // A-fragments: lane(quad,col) element j = x[b][n0+w*16+col][kt*32+quad*8+j]
    const float* xp = x + ((size_t)(b * NSZ) + n0 + w * 16 + col) * FDIM + quad * 8;
    int4 afr[4];
#pragma unroll
    for (int kt = 0; kt < 4; kt++) {
        float4 xa = *(const float4*)(xp + kt * 32);
        float4 xb = *(const float4*)(xp + kt * 32 + 4);
        afr[kt] = make_int4((int)bfpack(xa.x, xa.y), (int)bfpack(xa.z, xa.w),
                            (int)bfpack(xb.x, xb.y), (int)bfpack(xb.z, xb.w));
    }
    __syncthreads();

    // build W B-frags from LDS and run 8 MFMAs
    f32x4 alo = {0.f, 0.f, 0.f, 0.f};
    f32x4 ahi = {0.f, 0.f, 0.f, 0.f};
#pragma unroll
    for (int kt = 0; kt < 4; kt++) {
        short8 a8 = __builtin_bit_cast(short8, afr[kt]);
#pragma unroll
        for (int ot = 0; ot < 2; ot++) {
            unsigned d[4];
#pragma unroll
            for (int jp = 0; jp < 4; jp++) {
                float lo = wsl[(kt * 32 + quad * 8 + 2 * jp) * 33 + ot * 16 + col];
                float hi = wsl[(kt * 32 + quad * 8 + 2 * jp + 1) * 33 + ot * 16 + col];
                d[jp] = bfpack(lo, hi);
            }
            int4 bf = make_int4((int)d[0], (int)d[1], (int)d[2], (int)d[3]);
            if (ot == 0)
                alo = __builtin_amdgcn_mfma_f32_16x16x32_bf16(a8,
                        __builtin_bit_cast(short8, bf), alo, 0, 0, 0);
            else
                ahi = __builtin_amdgcn_mfma_f32_16x16x32_bf16(a8,
                        __builtin_bit_cast(short8, bf), ahi, 0, 0, 0);
        }
    }

    // alphas: reduce Wh[row]*a over o (col lanes), then exp factors.
    // eap stores R_i = EA2/EA = exp(-0.8*pa): softmax ratio cancels EA_i.
    float as0 = a_src[h * ODIM + col], as1 = a_src[h * ODIM + 16 + col];
    float ad0 = a_dst[h * ODIM + col], ad1 = a_dst[h * ODIM + 16 + col];
#pragma unroll
    for (int r = 0; r < 4; r++) {
        float pa = alo[r] * as0 + ahi[r] * as1;
        float pb = alo[r] * ad0 + ahi[r] * ad1;
#pragma unroll
        for (int mk = 1; mk <= 8; mk <<= 1) {
            pa += __shfl_xor(pa, mk);
            pb += __shfl_xor(pb, mk);
        }
        if (col == 0) {
            size_t idx = (size_t)(b * HH + h) * NSZ + n0 + w * 16 + quad * 4 + r;
            eap[idx]  = __expf(-0.8f * pa);
            ebe[idx]  = __expf(pb - 8.f);
            ebe2[idx] = __expf(0.2f * pb - 8.f);
        }
    }

    // Wh -> LDS (bf16), then gather B-fragments: wave w does (jl=w>>1, ot=w&1)
#pragma unroll
    for (int r = 0; r < 4; r++) {
        wlds[w * 16 + quad * 4 + r][col]      = (unsigned short)(bfbits(alo[r]) >> 16);
        wlds[w * 16 + quad * 4 + r][col + 16] = (unsigned short)(bfbits(ahi[r]) >> 16);
    }
    __syncthreads();
    int jl = w >> 1, ot = w & 1;
    unsigned d[4];
#pragma unroll
    for (int jp = 0; jp < 4; jp++) {
        unsigned lo = wlds[jl * 32 + quad * 8 + 2 * jp][ot * 16 + col];
        unsigned hi = wlds[jl * 32 + quad * 8 + 2 * jp + 1][ot * 16 + col];
        d[jp] = (hi << 16) | lo;
    }
    int fragid = ((b * HH + h) * 64 + nt * 2 + jl) * 2 + ot;
    whf[(size_t)fragid * 64 + lane] = make_int4((int)d[0], (int)d[1], (int)d[2], (int)d[3]);
}

// expand mask bits (B, B+1) of w into a dword half-mask:
// bot16 = -bit(B), top16 = -bit(B+1). 3 VALU, no LDS.
template<int B>
__device__ __forceinline__ unsigned mexp2(unsigned w, unsigned selhi) {
    unsigned lo, hi, r;
    asm("v_bfe_i32 %0, %1, %2, 1" : "=v"(lo) : "v"(w), "i"(B));
    asm("v_bfe_i32 %0, %1, %2, 1" : "=v"(hi) : "v"(w), "i"(B + 1));
    asm("v_bfi_b32 %0, %1, %2, %3" : "=v"(r) : "s"(selhi), "v"(hi), "v"(lo));
    return r;
}

// masked q-fragment: 8 j's -> bf16x8 A-frag. Row-scale-cancelled form:
// q_k = max(EB_k, R*EB2_k), then v_cvt_pk_bf16_f32 x4, masks via bfe/bfi.
__device__ __forceinline__ int4 pfrag(float R,
                                      f32x4 e0, f32x4 e1, f32x4 g0, f32x4 g1,
                                      unsigned w8, unsigned selhi) {
    float q0 = fmaxf(e0.x, R * g0.x);
    float q1 = fmaxf(e0.y, R * g0.y);
    float q2 = fmaxf(e0.z, R * g0.z);
    float q3 = fmaxf(e0.w, R * g0.w);
    float q4 = fmaxf(e1.x, R * g1.x);
    float q5 = fmaxf(e1.y, R * g1.y);
    float q6 = fmaxf(e1.z, R * g1.z);
    float q7 = fmaxf(e1.w, R * g1.w);
    unsigned d0, d1, d2, d3;
    asm("v_cvt_pk_bf16_f32 %0, %1, %2" : "=v"(d0) : "v"(q0), "v"(q1));
    asm("v_cvt_pk_bf16_f32 %0, %1, %2" : "=v"(d1) : "v"(q2), "v"(q3));
    asm("v_cvt_pk_bf16_f32 %0, %1, %2" : "=v"(d2) : "v"(q4), "v"(q5));
    asm("v_cvt_pk_bf16_f32 %0, %1, %2" : "=v"(d3) : "v"(q6), "v"(q7));
    return make_int4((int)(d0 & mexp2<0>(w8, selhi)),
                     (int)(d1 & mexp2<2>(w8, selhi)),
                     (int)(d2 & mexp2<4>(w8, selhi)),
                     (int)(d3 & mexp2<6>(w8, selhi)));
}

// ---------------------------------------------------------------------------
// Fused masked-softmax aggregation -- MEASUREMENT BUILD.
// Identical to R7 except the main loop runs TWICE (rep loop): numerator and
// denominator both accumulate exactly 2x, so output = (2a)/(2b) = a/b
// bit-identically. The memory clobber between reps forces the second pass to
// re-issue its loads. Purpose: (1) lift k_gat above the 40us top-5 cutoff so
// rocprof finally reports its counters; (2) the marginal dur vs R7 is the
// true serial cost of one loop pass (vs fixed staging/combine cost).
// ---------------------------------------------------------------------------
__global__ __launch_bounds__(256) void k_gat(const int4* __restrict__ whf,
                                             const float* __restrict__ eap,
                                             const float* __restrict__ ebe,
                                             const float* __restrict__ ebe2,
                                             const unsigned* __restrict__ adjb,
                                             float* __restrict__ out) {
    __shared__ __align__(16) float smem[4096];  // 16KB
    float* eble = smem;                         // EB [2048]
    float* eblf = smem + 2048;                  // EB2[2048]

    int t = threadIdx.x;
    int u = blockIdx.x;
    // XCD swizzle: XCD x gets units [x*512,(x+1)*512) = 4 consecutive (b,h)
    int unit = (u & 7) * 512 + (u >> 3);
    int b = unit >> 10;
    int h = (unit >> 7) & 7;
    int i0 = (unit & 127) * 16;
    int wave = t >> 6, lane = t & 63;
    int col = lane & 15, quad = lane >> 4, qsh = quad * 8;
    size_t bh = (size_t)(b * HH + h);
    const unsigned selhi = 0xFFFF0000u;

    // stage EB/EB2 tables: 2x 2048 floats, coalesced
    const float4* ege = (const float4*)(ebe + bh * NSZ);
    const float4* egf = (const float4*)(ebe2 + bh * NSZ);
    ((float4*)eble)[t]       = ege[t];
    ((float4*)eble)[t + 256] = ege[t + 256];
    ((float4*)eblf)[t]       = egf[t];
    ((float4*)eblf)[t + 256] = egf[t + 256];

    // row factor: R for row = i0 + col
    float R = eap[bh * NSZ + i0 + col];
    // mask base: row (i0+col), words [wave*16 .. wave*16+16)
    const char* mbase = (const char*)(adjb + ((size_t)(b * NSZ) + i0 + col) * 64)
                        + (size_t)wave * 64;
    const int4* bfp = whf + bh * 8192 + (size_t)(wave * 16) * 128 + lane;

    f32x4 a0 = {0.f, 0.f, 0.f, 0.f};
    f32x4 a1 = {0.f, 0.f, 0.f, 0.f};
    f32x4 ad = {0.f, 0.f, 0.f, 0.f};
    const int4 onesv = make_int4(0x3F803F80, 0x3F803F80, 0x3F803F80, 0x3F803F80);
    short8 bones = __builtin_bit_cast(short8, onesv);

    __syncthreads();

    for (int rep = 0; rep < 2; rep++) {
        for (int g = 0; g < 4; g++) {
            // batched load phase: 9 independent global loads in flight
            uint4 m0 = *(const uint4*)(mbase + g * 16);
            int4 blo[4], bhi[4];
#pragma unroll
            for (int q = 0; q < 4; q++) {
                blo[q] = bfp[(g * 4 + q) * 128];
                bhi[q] = bfp[(g * 4 + q) * 128 + 64];
            }
            unsigned ma[4] = {m0.x, m0.y, m0.z, m0.w};
#pragma unroll
            for (int q = 0; q < 4; q++) {
                int jt = wave * 16 + g * 4 + q;
                const f32x4* pe = (const f32x4*)&eble[jt * 32 + qsh];
                const f32x4* pf = (const f32x4*)&eblf[jt * 32 + qsh];
                f32x4 e0 = pe[0], e1 = pe[1];
                f32x4 g0 = pf[0], g1 = pf[1];
                int4 fr = pfrag(R, e0, e1, g0, g1, ma[q] >> qsh, selhi);
                short8 af = __builtin_bit_cast(short8, fr);
                short8 b0 = __builtin_bit_cast(short8, blo[q]);
                short8 b1 = __builtin_bit_cast(short8, bhi[q]);
                a0 = __builtin_amdgcn_mfma_f32_16x16x32_bf16(af, b0, a0, 0, 0, 0);
                a1 = __builtin_amdgcn_mfma_f32_16x16x32_bf16(af, b1, a1, 0, 0, 0);
                ad = __builtin_amdgcn_mfma_f32_16x16x32_bf16(af, bones, ad, 0, 0, 0);
            }
        }
        // force the second pass to re-issue loads (no CSE across reps)
        asm volatile("" ::: "memory");
    }

    // combine 4 jt-quarter partials -> wave 0 (reuses eb LDS; 6KB)
    f32x4 (*cb)[3][64] = (f32x4 (*)[3][64])smem;
    __syncthreads();                 // eb reads done; buffer dead
    if (wave >= 2) {
        cb[wave - 2][0][lane] = a0;
        cb[wave - 2][1][lane] = a1;
        cb[wave - 2][2][lane] = ad;
    }
    __syncthreads();
    if (wave < 2) {
        a0 += cb[wave][0][lane];
        a1 += cb[wave][1][lane];
        ad += cb[wave][2][lane];
    }
    __syncthreads();
    if (wave == 1) {
        cb[0][0][lane] = a0;
        cb[0][1][lane] = a1;
        cb[0][2][lane] = ad;
    }
    __syncthreads();
    if (wave != 0) return;
    a0 += cb[0][0][lane];
    a1 += cb[0][1][lane];
    ad += cb[0][2][lane];

    // epilogue: C/D layout col=lane&15, row=quad*4+reg; ad[r] = denominator
    // (a0, ad both 2x-accumulated -> ratio unchanged)
    float* op = out + ((size_t)(b * NSZ) + i0) * (HH * ODIM) + h * ODIM + col;
#pragma unroll
    for (int r = 0; r < 4; r++) {
        int row = quad * 4 + r;
        float inv = 1.0f / ad[r];
        op[(size_t)row * (HH * ODIM)]      = fmaxf(a0[r] * inv, 0.f);
        op[(size_t)row * (HH * ODIM) + 16] = fmaxf(a1[r] * inv, 0.f);
    }
}

extern "C" void kernel_launch(void* const* d_in, const int* in_sizes, int n_in,
                              void* d_out, int out_size, void* d_ws, size_t ws_size,
                              hipStream_t stream) {
    const float* x     = (const float*)d_in[0];
    const float* adj   = (const float*)d_in[1];
    const float* W     = (const float*)d_in[2];
    const float* a_src = (const float*)d_in[3];
    const float* a_dst = (const float*)d_in[4];
    float* out = (float*)d_out;

    float* ws = (float*)d_ws;
    float* eap     = ws + WS_EAP;
    float* ebe     = ws + WS_EBP;
    float* ebe2    = ws + WS_EBP + 65536;
    unsigned* adjb = (unsigned*)(ws + WS_ADJB);
    int4* whf      = (int4*)(ws + WS_WHF);

    // fused prep: 1024 MFMA-projection blocks first, then 4096 adj blocks
    k_prep<<<dim3(1024 + 4096), dim3(256), 0, stream>>>(x, adj, W, a_src, a_dst,
                                                        adjb, whf, eap, ebe, ebe2);
    // fused masked softmax + MFMA aggregation: 4096 blocks x 4 waves
    k_gat<<<dim3(BB * HH * (NSZ / 16)), dim3(256), 0, stream>>>(whf, eap, ebe, ebe2, adjb, out);
}

// Round 9
// 133.073 us; speedup vs baseline: 1.2264x; 1.2264x over previous
//
#include <hip/hip_runtime.h>
#include <math.h>

#define BB 4
#define NSZ 2048
#define FDIM 128
#define ODIM 32
#define HH 8

typedef short short8 __attribute__((ext_vector_type(8)));
typedef _Float16 half8 __attribute__((ext_vector_type(8)));
typedef float f32x4 __attribute__((ext_vector_type(4)));

// workspace layout (float units)
#define WS_EAP  0                 // float[B*H*N]  R_i = exp(-0.8 a_i)
#define WS_EBP  131072            // f16 EB[B*H*N] + f16 EB2[B*H*N]
#define WS_ADJB 262144            // u32[B*N*64]
#define WS_WHF  786432            // f16 Wh B-frags (4MB)
// whf: int4[((b*H+h)*64 + jt)*2 + ot][64 lanes]

// pack 2 f32 -> 2 f16 (RTZ) in one dword
__device__ __forceinline__ unsigned hpack(float a, float b) {
    unsigned r;
    asm("v_cvt_pkrtz_f16_f32 %0, %1, %2" : "=v"(r) : "v"(a), "v"(b));
    return r;
}

// ---------------------------------------------------------------------------
// Fused prep. Blocks [0,1024): MFMA projection for one (b,h,64 n-rows).
// Blocks [1024,1024+4096): adj bitmask pack, grid-strided 4 chunks/block.
// ---------------------------------------------------------------------------
__global__ __launch_bounds__(256) void k_prep(const float* __restrict__ x,
                                              const float* __restrict__ adj,
                                              const float* __restrict__ W,
                                              const float* __restrict__ a_src,
                                              const float* __restrict__ a_dst,
                                              unsigned* __restrict__ adjb,
                                              int4* __restrict__ whf,
                                              float* __restrict__ eap,
                                              unsigned short* __restrict__ ebe,
                                              unsigned short* __restrict__ ebe2) {
    __shared__ float wsl[FDIM * 33];          // W[h] staged, row-padded (k*33+o)
    __shared__ unsigned short wlds[64][33];   // f16 Wh tile [local n][o], +1 pad
    int t = threadIdx.x;

    if (blockIdx.x >= 1024) {
        // ---------------- adj bitmask part (4 chunks, MLP x4) ----------------
        int bid = blockIdx.x - 1024;
#pragma unroll
        for (int it = 0; it < 4; it++) {
            int g = (it * 4096 + bid) * 256 + t;
            int l = g & 7;
            int word = g >> 3;
            int wk = word & 63;
            int row = word >> 6;
            int i = row & (NSZ - 1);
            const float4 v = *(const float4*)&adj[(size_t)row * NSZ + wk * 32 + l * 4];
            unsigned m = 0;
            if (v.x > 0.f) m |= 1u << (l * 4 + 0);
            if (v.y > 0.f) m |= 1u << (l * 4 + 1);
            if (v.z > 0.f) m |= 1u << (l * 4 + 2);
            if (v.w > 0.f) m |= 1u << (l * 4 + 3);
            m |= (unsigned)__shfl_xor((int)m, 1);
            m |= (unsigned)__shfl_xor((int)m, 2);
            m |= (unsigned)__shfl_xor((int)m, 4);
            if (l == 0) {
                int jb = i - wk * 32;
                if (jb >= 0 && jb < 32) m |= 1u << jb;  // self-loop
                adjb[word] = m;
            }
        }
        return;
    }

    // ---------------- projection part ----------------
    int bidx = blockIdx.x;                      // [0,1024): b(2) h(3) nt(5)
    int b = bidx >> 8;
    int h = (bidx >> 5) & 7;
    int nt = bidx & 31;
    int n0 = nt * 64;
    int w = t >> 6, lane = t & 63;
    int col = lane & 15, quad = lane >> 4;

    // stage W[h] (4096 floats) coalesced into padded LDS
#pragma unroll
    for (int m = 0; m < 16; m++) {
        int idx = t + m * 256;
        wsl[(idx >> 5) * 33 + (idx & 31)] = W[(size_t)h * (FDIM * ODIM) + idx];
    }

    // A-fragments (f16): lane(quad,col) elem j = x[b][n0+w*16+col][kt*32+quad*8+j]
    const float* xp = x + ((size_t)(b * NSZ) + n0 + w * 16 + col) * FDIM + quad * 8;
    int4 afr[4];
#pragma unroll
    for (int kt = 0; kt < 4; kt++) {
        float4 xa = *(const float4*)(xp + kt * 32);
        float4 xb = *(const float4*)(xp + kt * 32 + 4);
        afr[kt] = make_int4((int)hpack(xa.x, xa.y), (int)hpack(xa.z, xa.w),
                            (int)hpack(xb.x, xb.y), (int)hpack(xb.z, xb.w));
    }
    __syncthreads();

    // build W B-frags (f16) from LDS and run 8 MFMAs
    f32x4 alo = {0.f, 0.f, 0.f, 0.f};
    f32x4 ahi = {0.f, 0.f, 0.f, 0.f};
#pragma unroll
    for (int kt = 0; kt < 4; kt++) {
        half8 a8 = __builtin_bit_cast(half8, afr[kt]);
#pragma unroll
        for (int ot = 0; ot < 2; ot++) {
            unsigned d[4];
#pragma unroll
            for (int jp = 0; jp < 4; jp++) {
                float lo = wsl[(kt * 32 + quad * 8 + 2 * jp) * 33 + ot * 16 + col];
                float hi = wsl[(kt * 32 + quad * 8 + 2 * jp + 1) * 33 + ot * 16 + col];
                d[jp] = hpack(lo, hi);
            }
            int4 bf = make_int4((int)d[0], (int)d[1], (int)d[2], (int)d[3]);
            if (ot == 0)
                alo = __builtin_amdgcn_mfma_f32_16x16x32_f16(a8,
                        __builtin_bit_cast(half8, bf), alo, 0, 0, 0);
            else
                ahi = __builtin_amdgcn_mfma_f32_16x16x32_f16(a8,
                        __builtin_bit_cast(half8, bf), ahi, 0, 0, 0);
        }
    }

    // alphas: reduce Wh[row]*a over o (col lanes), then exp factors.
    // R_i = exp(-0.8 pa) (f32); EB/EB2 stored f16 with offset -2 (f16-range-safe:
    // sigma_beta ~1.75 -> exp(beta-2) in [7e-5, 400] at 4.5 sigma).
    float as0 = a_src[h * ODIM + col], as1 = a_src[h * ODIM + 16 + col];
    float ad0 = a_dst[h * ODIM + col], ad1 = a_dst[h * ODIM + 16 + col];
#pragma unroll
    for (int r = 0; r < 4; r++) {
        float pa = alo[r] * as0 + ahi[r] * as1;
        float pb = alo[r] * ad0 + ahi[r] * ad1;
#pragma unroll
        for (int mk = 1; mk <= 8; mk <<= 1) {
            pa += __shfl_xor(pa, mk);
            pb += __shfl_xor(pb, mk);
        }
        if (col == 0) {
            size_t idx = (size_t)(b * HH + h) * NSZ + n0 + w * 16 + quad * 4 + r;
            eap[idx]  = __expf(-0.8f * pa);
            ebe[idx]  = (unsigned short)(hpack(__expf(pb - 2.f), 0.f) & 0xffffu);
            ebe2[idx] = (unsigned short)(hpack(__expf(0.2f * pb - 2.f), 0.f) & 0xffffu);
        }
    }

    // Wh -> LDS (f16), then gather B-fragments: wave w does (jl=w>>1, ot=w&1)
#pragma unroll
    for (int r = 0; r < 4; r++) {
        wlds[w * 16 + quad * 4 + r][col]      = (unsigned short)(hpack(alo[r], 0.f) & 0xffffu);
        wlds[w * 16 + quad * 4 + r][col + 16] = (unsigned short)(hpack(ahi[r], 0.f) & 0xffffu);
    }
    __syncthreads();
    int jl = w >> 1, ot = w & 1;
    unsigned d[4];
#pragma unroll
    for (int jp = 0; jp < 4; jp++) {
        unsigned lo = wlds[jl * 32 + quad * 8 + 2 * jp][ot * 16 + col];
        unsigned hi = wlds[jl * 32 + quad * 8 + 2 * jp + 1][ot * 16 + col];
        d[jp] = (hi << 16) | lo;
    }
    int fragid = ((b * HH + h) * 64 + nt * 2 + jl) * 2 + ot;
    whf[(size_t)fragid * 64 + lane] = make_int4((int)d[0], (int)d[1], (int)d[2], (int)d[3]);
}

// expand mask bits (B, B+1) of w into a dword half-mask:
// bot16 = -bit(B), top16 = -bit(B+1). 3 VALU, no LDS.
template<int B>
__device__ __forceinline__ unsigned mexp2(unsigned w, unsigned selhi) {
    unsigned lo, hi, r;
    asm("v_bfe_i32 %0, %1, %2, 1" : "=v"(lo) : "v"(w), "i"(B));
    asm("v_bfe_i32 %0, %1, %2, 1" : "=v"(hi) : "v"(w), "i"(B + 1));
    asm("v_bfi_b32 %0, %1, %2, %3" : "=v"(r) : "s"(selhi), "v"(hi), "v"(lo));
    return r;
}

// masked q-fragment, f16 packed: q = max(EB, R*EB2) via 4x v_pk_mul_f16 +
// 4x v_pk_max_f16; output dwords ARE the packed f16 A-frag (no cvt needed).
// Masks via bfe/bfi. Core: 8 pk + 16 mask-ish VALU, 0 LDS.
__device__ __forceinline__ int4 pfrag16(unsigned R2, uint4 e, uint4 g,
                                        unsigned w8, unsigned selhi) {
    unsigned r0, r1, r2, r3, q0, q1, q2, q3;
    asm("v_pk_mul_f16 %0, %1, %2" : "=v"(r0) : "v"(R2), "v"(g.x));
    asm("v_pk_mul_f16 %0, %1, %2" : "=v"(r1) : "v"(R2), "v"(g.y));
    asm("v_pk_mul_f16 %0, %1, %2" : "=v"(r2) : "v"(R2), "v"(g.z));
    asm("v_pk_mul_f16 %0, %1, %2" : "=v"(r3) : "v"(R2), "v"(g.w));
    asm("v_pk_max_f16 %0, %1, %2" : "=v"(q0) : "v"(e.x), "v"(r0));
    asm("v_pk_max_f16 %0, %1, %2" : "=v"(q1) : "v"(e.y), "v"(r1));
    asm("v_pk_max_f16 %0, %1, %2" : "=v"(q2) : "v"(e.z), "v"(r2));
    asm("v_pk_max_f16 %0, %1, %2" : "=v"(q3) : "v"(e.w), "v"(r3));
    return make_int4((int)(q0 & mexp2<0>(w8, selhi)),
                     (int)(q1 & mexp2<2>(w8, selhi)),
                     (int)(q2 & mexp2<4>(w8, selhi)),
                     (int)(q3 & mexp2<6>(w8, selhi)));
}

// ---------------------------------------------------------------------------
// Fused masked-softmax aggregation, f16 pipeline (R8 measured: loop was
// VALU-bound 73% AND LDS-co-bound (4x b128/q). f16 halves LDS reads (2/q)
// and packs mul+max 2-wide; pk_max output is the A-frag directly.
// Block = (b,h,16 i-rows): 4096 blocks x 4 waves; wave = jt-quarter (16 jt).
// ---------------------------------------------------------------------------
__global__ __launch_bounds__(256) void k_gat(const int4* __restrict__ whf,
                                             const float* __restrict__ eap,
                                             const unsigned short* __restrict__ ebe,
                                             const unsigned short* __restrict__ ebe2,
                                             const unsigned* __restrict__ adjb,
                                             float* __restrict__ out) {
    __shared__ __align__(16) float smem[2048];      // 8KB
    unsigned short* eble = (unsigned short*)smem;         // f16 EB [2048] (4KB)
    unsigned short* eblf = (unsigned short*)smem + 2048;  // f16 EB2[2048] (4KB)

    int t = threadIdx.x;
    int u = blockIdx.x;
    // XCD swizzle: XCD x gets units [x*512,(x+1)*512) = 4 consecutive (b,h)
    int unit = (u & 7) * 512 + (u >> 3);
    int b = unit >> 10;
    int h = (unit >> 7) & 7;
    int i0 = (unit & 127) * 16;
    int wave = t >> 6, lane = t & 63;
    int col = lane & 15, quad = lane >> 4, qsh = quad * 8;
    size_t bh = (size_t)(b * HH + h);
    const unsigned selhi = 0xFFFF0000u;

    // stage f16 EB/EB2 tables: 2x 4KB, one float4 per thread each
    const float4* ege = (const float4*)(ebe + bh * NSZ);
    const float4* egf = (const float4*)(ebe2 + bh * NSZ);
    ((float4*)eble)[t] = ege[t];
    ((float4*)eblf)[t] = egf[t];

    // row factor: R2 = {R,R} f16 for row = i0 + col
    float R = eap[bh * NSZ + i0 + col];
    unsigned R2 = hpack(R, R);
    // mask base: row (i0+col), words [wave*16 .. wave*16+16)
    const char* mbase = (const char*)(adjb + ((size_t)(b * NSZ) + i0 + col) * 64)
                        + (size_t)wave * 64;
    const int4* bfp = whf + bh * 8192 + (size_t)(wave * 16) * 128 + lane;

    f32x4 a0 = {0.f, 0.f, 0.f, 0.f};
    f32x4 a1 = {0.f, 0.f, 0.f, 0.f};
    f32x4 ad = {0.f, 0.f, 0.f, 0.f};
    const int4 onesv = make_int4(0x3C003C00, 0x3C003C00, 0x3C003C00, 0x3C003C00);
    half8 hones = __builtin_bit_cast(half8, onesv);

    __syncthreads();

    for (int g = 0; g < 4; g++) {
        // batched load phase: 9 independent global loads in flight
        uint4 m0 = *(const uint4*)(mbase + g * 16);
        int4 blo[4], bhi[4];
#pragma unroll
        for (int q = 0; q < 4; q++) {
            blo[q] = bfp[(g * 4 + q) * 128];
            bhi[q] = bfp[(g * 4 + q) * 128 + 64];
        }
        unsigned ma[4] = {m0.x, m0.y, m0.z, m0.w};
#pragma unroll
        for (int q = 0; q < 4; q++) {
            int jt = wave * 16 + g * 4 + q;
            uint4 ef = *(const uint4*)&eble[jt * 32 + qsh];   // 8 f16 EB
            uint4 gf = *(const uint4*)&eblf[jt * 32 + qsh];   // 8 f16 EB2
            int4 fr = pfrag16(R2, ef, gf, ma[q] >> qsh, selhi);
            half8 af = __builtin_bit_cast(half8, fr);
            half8 b0 = __builtin_bit_cast(half8, blo[q]);
            half8 b1 = __builtin_bit_cast(half8, bhi[q]);
            a0 = __builtin_amdgcn_mfma_f32_16x16x32_f16(af, b0, a0, 0, 0, 0);
            a1 = __builtin_amdgcn_mfma_f32_16x16x32_f16(af, b1, a1, 0, 0, 0);
            ad = __builtin_amdgcn_mfma_f32_16x16x32_f16(af, hones, ad, 0, 0, 0);
        }
    }

    // combine 4 jt-quarter partials -> wave 0 (reuses eb LDS; 6KB)
    f32x4 (*cb)[3][64] = (f32x4 (*)[3][64])smem;
    __syncthreads();                 // eb reads done; buffer dead
    if (wave >= 2) {
        cb[wave - 2][0][lane] = a0;
        cb[wave - 2][1][lane] = a1;
        cb[wave - 2][2][lane] = ad;
    }
    __syncthreads();
    if (wave < 2) {
        a0 += cb[wave][0][lane];
        a1 += cb[wave][1][lane];
        ad += cb[wave][2][lane];
    }
    __syncthreads();
    if (wave == 1) {
        cb[0][0][lane] = a0;
        cb[0][1][lane] = a1;
        cb[0][2][lane] = ad;
    }
    __syncthreads();
    if (wave != 0) return;
    a0 += cb[0][0][lane];
    a1 += cb[0][1][lane];
    ad += cb[0][2][lane];

    // epilogue: C/D layout col=lane&15, row=quad*4+reg; ad[r] = denominator
    float* op = out + ((size_t)(b * NSZ) + i0) * (HH * ODIM) + h * ODIM + col;
#pragma unroll
    for (int r = 0; r < 4; r++) {
        int row = quad * 4 + r;
        float inv = 1.0f / ad[r];
        op[(size_t)row * (HH * ODIM)]      = fmaxf(a0[r] * inv, 0.f);
        op[(size_t)row * (HH * ODIM) + 16] = fmaxf(a1[r] * inv, 0.f);
    }
}

extern "C" void kernel_launch(void* const* d_in, const int* in_sizes, int n_in,
                              void* d_out, int out_size, void* d_ws, size_t ws_size,
                              hipStream_t stream) {
    const float* x     = (const float*)d_in[0];
    const float* adj   = (const float*)d_in[1];
    const float* W     = (const float*)d_in[2];
    const float* a_src = (const float*)d_in[3];
    const float* a_dst = (const float*)d_in[4];
    float* out = (float*)d_out;

    float* ws = (float*)d_ws;
    float* eap            = ws + WS_EAP;
    unsigned short* ebe   = (unsigned short*)(ws + WS_EBP);
    unsigned short* ebe2  = (unsigned short*)(ws + WS_EBP + 65536);
    unsigned* adjb        = (unsigned*)(ws + WS_ADJB);
    int4* whf             = (int4*)(ws + WS_WHF);

    // fused prep: 1024 MFMA-projection blocks first, then 4096 adj blocks
    k_prep<<<dim3(1024 + 4096), dim3(256), 0, stream>>>(x, adj, W, a_src, a_dst,
                                                        adjb, whf, eap, ebe, ebe2);
    // fused masked softmax + MFMA aggregation: 4096 blocks x 4 waves
    k_gat<<<dim3(BB * HH * (NSZ / 16)), dim3(256), 0, stream>>>(whf, eap, ebe, ebe2, adjb, out);
}

// Round 10
// 130.081 us; speedup vs baseline: 1.2546x; 1.0230x over previous
//
#include <hip/hip_runtime.h>
#include <math.h>

#define BB 4
#define NSZ 2048
#define FDIM 128
#define ODIM 32
#define HH 8

typedef short short8 __attribute__((ext_vector_type(8)));
typedef _Float16 half8 __attribute__((ext_vector_type(8)));
typedef float f32x4 __attribute__((ext_vector_type(4)));

// workspace layout (float units)
#define WS_EAP  0                 // float[B*H*N]  R_i = exp(-0.8 a_i)
#define WS_EBP  131072            // f16 EB[B*H*N] + f16 EB2[B*H*N]
#define WS_ADJB 262144            // u32[B*N*64]
#define WS_WHF  786432            // f16 Wh B-frags (4MB)
// whf: int4[((b*H+h)*64 + jt)*2 + ot][64 lanes]

// pack 2 f32 -> 2 f16 (RTZ) in one dword
__device__ __forceinline__ unsigned hpack(float a, float b) {
    unsigned r;
    asm("v_cvt_pkrtz_f16_f32 %0, %1, %2" : "=v"(r) : "v"(a), "v"(b));
    return r;
}

// ---------------------------------------------------------------------------
// Fused prep. Blocks [0,1024): MFMA projection for one (b,h,64 n-rows).
// Blocks [1024,1024+4096): adj bitmask pack, grid-strided 4 chunks/block.
// ---------------------------------------------------------------------------
__global__ __launch_bounds__(256) void k_prep(const float* __restrict__ x,
                                              const float* __restrict__ adj,
                                              const float* __restrict__ W,
                                              const float* __restrict__ a_src,
                                              const float* __restrict__ a_dst,
                                              unsigned* __restrict__ adjb,
                                              int4* __restrict__ whf,
                                              float* __restrict__ eap,
                                              unsigned short* __restrict__ ebe,
                                              unsigned short* __restrict__ ebe2) {
    __shared__ float wsl[FDIM * 33];          // W[h] staged, row-padded (k*33+o)
    __shared__ unsigned short wlds[64][33];   // f16 Wh tile [local n][o], +1 pad
    int t = threadIdx.x;

    if (blockIdx.x >= 1024) {
        // ---------------- adj bitmask part (4 chunks, MLP x4) ----------------
        int bid = blockIdx.x - 1024;
#pragma unroll
        for (int it = 0; it < 4; it++) {
            int g = (it * 4096 + bid) * 256 + t;
            int l = g & 7;
            int word = g >> 3;
            int wk = word & 63;
            int row = word >> 6;
            int i = row & (NSZ - 1);
            const float4 v = *(const float4*)&adj[(size_t)row * NSZ + wk * 32 + l * 4];
            unsigned m = 0;
            if (v.x > 0.f) m |= 1u << (l * 4 + 0);
            if (v.y > 0.f) m |= 1u << (l * 4 + 1);
            if (v.z > 0.f) m |= 1u << (l * 4 + 2);
            if (v.w > 0.f) m |= 1u << (l * 4 + 3);
            m |= (unsigned)__shfl_xor((int)m, 1);
            m |= (unsigned)__shfl_xor((int)m, 2);
            m |= (unsigned)__shfl_xor((int)m, 4);
            if (l == 0) {
                int jb = i - wk * 32;
                if (jb >= 0 && jb < 32) m |= 1u << jb;  // self-loop
                adjb[word] = m;
            }
        }
        return;
    }

    // ---------------- projection part ----------------
    int bidx = blockIdx.x;                      // [0,1024): b(2) h(3) nt(5)
    int b = bidx >> 8;
    int h = (bidx >> 5) & 7;
    int nt = bidx & 31;
    int n0 = nt * 64;
    int w = t >> 6, lane = t & 63;
    int col = lane & 15, quad = lane >> 4;

    // stage W[h] (4096 floats) coalesced into padded LDS
#pragma unroll
    for (int m = 0; m < 16; m++) {
        int idx = t + m * 256;
        wsl[(idx >> 5) * 33 + (idx & 31)] = W[(size_t)h * (FDIM * ODIM) + idx];
    }

    // A-fragments (f16): lane(quad,col) elem j = x[b][n0+w*16+col][kt*32+quad*8+j]
    const float* xp = x + ((size_t)(b * NSZ) + n0 + w * 16 + col) * FDIM + quad * 8;
    int4 afr[4];
#pragma unroll
    for (int kt = 0; kt < 4; kt++) {
        float4 xa = *(const float4*)(xp + kt * 32);
        float4 xb = *(const float4*)(xp + kt * 32 + 4);
        afr[kt] = make_int4((int)hpack(xa.x, xa.y), (int)hpack(xa.z, xa.w),
                            (int)hpack(xb.x, xb.y), (int)hpack(xb.z, xb.w));
    }
    __syncthreads();

    // build W B-frags (f16) from LDS and run 8 MFMAs
    f32x4 alo = {0.f, 0.f, 0.f, 0.f};
    f32x4 ahi = {0.f, 0.f, 0.f, 0.f};
#pragma unroll
    for (int kt = 0; kt < 4; kt++) {
        half8 a8 = __builtin_bit_cast(half8, afr[kt]);
#pragma unroll
        for (int ot = 0; ot < 2; ot++) {
            unsigned d[4];
#pragma unroll
            for (int jp = 0; jp < 4; jp++) {
                float lo = wsl[(kt * 32 + quad * 8 + 2 * jp) * 33 + ot * 16 + col];
                float hi = wsl[(kt * 32 + quad * 8 + 2 * jp + 1) * 33 + ot * 16 + col];
                d[jp] = hpack(lo, hi);
            }
            int4 bf = make_int4((int)d[0], (int)d[1], (int)d[2], (int)d[3]);
            if (ot == 0)
                alo = __builtin_amdgcn_mfma_f32_16x16x32_f16(a8,
                        __builtin_bit_cast(half8, bf), alo, 0, 0, 0);
            else
                ahi = __builtin_amdgcn_mfma_f32_16x16x32_f16(a8,
                        __builtin_bit_cast(half8, bf), ahi, 0, 0, 0);
        }
    }

    // alphas: reduce Wh[row]*a over o (col lanes), then exp factors.
    // R_i = exp(-0.8 pa) (f32); EB/EB2 stored f16 with offset -2 (f16-range-safe).
    float as0 = a_src[h * ODIM + col], as1 = a_src[h * ODIM + 16 + col];
    float ad0 = a_dst[h * ODIM + col], ad1 = a_dst[h * ODIM + 16 + col];
#pragma unroll
    for (int r = 0; r < 4; r++) {
        float pa = alo[r] * as0 + ahi[r] * as1;
        float pb = alo[r] * ad0 + ahi[r] * ad1;
#pragma unroll
        for (int mk = 1; mk <= 8; mk <<= 1) {
            pa += __shfl_xor(pa, mk);
            pb += __shfl_xor(pb, mk);
        }
        if (col == 0) {
            size_t idx = (size_t)(b * HH + h) * NSZ + n0 + w * 16 + quad * 4 + r;
            eap[idx]  = __expf(-0.8f * pa);
            ebe[idx]  = (unsigned short)(hpack(__expf(pb - 2.f), 0.f) & 0xffffu);
            ebe2[idx] = (unsigned short)(hpack(__expf(0.2f * pb - 2.f), 0.f) & 0xffffu);
        }
    }

    // Wh -> LDS (f16), then gather B-fragments: wave w does (jl=w>>1, ot=w&1)
#pragma unroll
    for (int r = 0; r < 4; r++) {
        wlds[w * 16 + quad * 4 + r][col]      = (unsigned short)(hpack(alo[r], 0.f) & 0xffffu);
        wlds[w * 16 + quad * 4 + r][col + 16] = (unsigned short)(hpack(ahi[r], 0.f) & 0xffffu);
    }
    __syncthreads();
    int jl = w >> 1, ot = w & 1;
    unsigned d[4];
#pragma unroll
    for (int jp = 0; jp < 4; jp++) {
        unsigned lo = wlds[jl * 32 + quad * 8 + 2 * jp][ot * 16 + col];
        unsigned hi = wlds[jl * 32 + quad * 8 + 2 * jp + 1][ot * 16 + col];
        d[jp] = (hi << 16) | lo;
    }
    int fragid = ((b * HH + h) * 64 + nt * 2 + jl) * 2 + ot;
    whf[(size_t)fragid * 64 + lane] = make_int4((int)d[0], (int)d[1], (int)d[2], (int)d[3]);
}

// expand mask bits (B, B+1) of w into a dword half-mask:
// bot16 = -bit(B), top16 = -bit(B+1). 3 VALU, no LDS.
template<int B>
__device__ __forceinline__ unsigned mexp2(unsigned w, unsigned selhi) {
    unsigned lo, hi, r;
    asm("v_bfe_i32 %0, %1, %2, 1" : "=v"(lo) : "v"(w), "i"(B));
    asm("v_bfe_i32 %0, %1, %2, 1" : "=v"(hi) : "v"(w), "i"(B + 1));
    asm("v_bfi_b32 %0, %1, %2, %3" : "=v"(r) : "s"(selhi), "v"(hi), "v"(lo));
    return r;
}

// masked q-fragment, f16 packed: q = max(EB, R*EB2) via 4x v_pk_mul_f16 +
// 4x v_pk_max_f16; output dwords ARE the packed f16 A-frag (no cvt needed).
__device__ __forceinline__ int4 pfrag16(unsigned R2, uint4 e, uint4 g,
                                        unsigned w8, unsigned selhi) {
    unsigned r0, r1, r2, r3, q0, q1, q2, q3;
    asm("v_pk_mul_f16 %0, %1, %2" : "=v"(r0) : "v"(R2), "v"(g.x));
    asm("v_pk_mul_f16 %0, %1, %2" : "=v"(r1) : "v"(R2), "v"(g.y));
    asm("v_pk_mul_f16 %0, %1, %2" : "=v"(r2) : "v"(R2), "v"(g.z));
    asm("v_pk_mul_f16 %0, %1, %2" : "=v"(r3) : "v"(R2), "v"(g.w));
    asm("v_pk_max_f16 %0, %1, %2" : "=v"(q0) : "v"(e.x), "v"(r0));
    asm("v_pk_max_f16 %0, %1, %2" : "=v"(q1) : "v"(e.y), "v"(r1));
    asm("v_pk_max_f16 %0, %1, %2" : "=v"(q2) : "v"(e.z), "v"(r2));
    asm("v_pk_max_f16 %0, %1, %2" : "=v"(q3) : "v"(e.w), "v"(r3));
    return make_int4((int)(q0 & mexp2<0>(w8, selhi)),
                     (int)(q1 & mexp2<2>(w8, selhi)),
                     (int)(q2 & mexp2<4>(w8, selhi)),
                     (int)(q3 & mexp2<6>(w8, selhi)));
}

// ---------------------------------------------------------------------------
// Fused masked-softmax aggregation, f16 pipeline + amortized fixed cost.
// Block = (b,h,32 i-rows): 2048 blocks x 4 waves; wave = jt-quarter (16 jt)
// over BOTH i-tiles (R5 geometry). With the loop halved by f16 (R9), the
// per-block fixed cost (staging, prologue, launch) is the bigger k_gat term;
// halving block count halves it, and each whf load now feeds 2 pfrags.
// Combine: R5's verified cross-swap scheme (12KB, reuses dead eb LDS).
// ---------------------------------------------------------------------------
__global__ __launch_bounds__(256) void k_gat(const int4* __restrict__ whf,
                                             const float* __restrict__ eap,
                                             const unsigned short* __restrict__ ebe,
                                             const unsigned short* __restrict__ ebe2,
                                             const unsigned* __restrict__ adjb,
                                             float* __restrict__ out) {
    __shared__ __align__(16) float smem[3072];            // 12KB
    unsigned short* eble = (unsigned short*)smem;         // f16 EB [2048] (4KB)
    unsigned short* eblf = (unsigned short*)smem + 2048;  // f16 EB2[2048] (4KB)

    int t = threadIdx.x;
    int u = blockIdx.x;
    // XCD swizzle: XCD x gets units [x*256,(x+1)*256) = 4 consecutive (b,h)
    int unit = (u & 7) * 256 + (u >> 3);
    int b = unit >> 9;
    int h = (unit >> 6) & 7;
    int i0 = (unit & 63) * 32;
    int wave = t >> 6, lane = t & 63;
    int col = lane & 15, quad = lane >> 4, qsh = quad * 8;
    size_t bh = (size_t)(b * HH + h);
    const unsigned selhi = 0xFFFF0000u;

    // stage f16 EB/EB2 tables: 2x 4KB, one float4 per thread each
    const float4* ege = (const float4*)(ebe + bh * NSZ);
    const float4* egf = (const float4*)(ebe2 + bh * NSZ);
    ((float4*)eble)[t] = ege[t];
    ((float4*)eblf)[t] = egf[t];

    // row factors for the two i-tiles: rows i0+col and i0+16+col
    float Ra = eap[bh * NSZ + i0 + col];
    float Rb = eap[bh * NSZ + i0 + 16 + col];
    unsigned R20 = hpack(Ra, Ra);
    unsigned R21 = hpack(Rb, Rb);
    // mask base: row (i0+tt*16+col), words [wave*16 .. wave*16+16)
    const char* mbase = (const char*)(adjb + ((size_t)(b * NSZ) + i0 + col) * 64)
                        + (size_t)wave * 64;
    const int4* bfp = whf + bh * 8192 + (size_t)(wave * 16) * 128 + lane;

    f32x4 a00 = {0.f,0.f,0.f,0.f}, a01 = {0.f,0.f,0.f,0.f}, a0d = {0.f,0.f,0.f,0.f};
    f32x4 a10 = {0.f,0.f,0.f,0.f}, a11 = {0.f,0.f,0.f,0.f}, a1d = {0.f,0.f,0.f,0.f};
    const int4 onesv = make_int4(0x3C003C00, 0x3C003C00, 0x3C003C00, 0x3C003C00);
    half8 hones = __builtin_bit_cast(half8, onesv);

    __syncthreads();

    for (int g = 0; g < 4; g++) {
        // batched load phase: 10 independent global loads in flight
        uint4 m0 = *(const uint4*)(mbase + 0 * 4096 + g * 16);
        uint4 m1 = *(const uint4*)(mbase + 1 * 4096 + g * 16);
        int4 blo[4], bhi[4];
#pragma unroll
        for (int q = 0; q < 4; q++) {
            blo[q] = bfp[(g * 4 + q) * 128];
            bhi[q] = bfp[(g * 4 + q) * 128 + 64];
        }
        unsigned ma0[4] = {m0.x, m0.y, m0.z, m0.w};
        unsigned ma1[4] = {m1.x, m1.y, m1.z, m1.w};
#pragma unroll
        for (int q = 0; q < 4; q++) {
            int jt = wave * 16 + g * 4 + q;
            uint4 ef = *(const uint4*)&eble[jt * 32 + qsh];   // 8 f16 EB
            uint4 gf = *(const uint4*)&eblf[jt * 32 + qsh];   // 8 f16 EB2
            half8 b0 = __builtin_bit_cast(half8, blo[q]);
            half8 b1 = __builtin_bit_cast(half8, bhi[q]);
            int4 f0 = pfrag16(R20, ef, gf, ma0[q] >> qsh, selhi);
            int4 f1 = pfrag16(R21, ef, gf, ma1[q] >> qsh, selhi);
            half8 af0 = __builtin_bit_cast(half8, f0);
            half8 af1 = __builtin_bit_cast(half8, f1);
            a00 = __builtin_amdgcn_mfma_f32_16x16x32_f16(af0, b0, a00, 0, 0, 0);
            a01 = __builtin_amdgcn_mfma_f32_16x16x32_f16(af0, b1, a01, 0, 0, 0);
            a0d = __builtin_amdgcn_mfma_f32_16x16x32_f16(af0, hones, a0d, 0, 0, 0);
            a10 = __builtin_amdgcn_mfma_f32_16x16x32_f16(af1, b0, a10, 0, 0, 0);
            a11 = __builtin_amdgcn_mfma_f32_16x16x32_f16(af1, b1, a11, 0, 0, 0);
            a1d = __builtin_amdgcn_mfma_f32_16x16x32_f16(af1, hones, a1d, 0, 0, 0);
        }
    }

    // tree combine of 4 jt-quarter partials (R5 scheme; reuses eb LDS, 12KB)
    f32x4 (*cb)[3][64] = (f32x4 (*)[3][64])smem;
    __syncthreads();                 // eb reads done; buffer dead
    if (wave >= 2) {
        int s = (wave - 2) * 2;
        cb[s][0][lane] = a00;  cb[s][1][lane] = a01;  cb[s][2][lane] = a0d;
        cb[s + 1][0][lane] = a10;  cb[s + 1][1][lane] = a11;  cb[s + 1][2][lane] = a1d;
    }
    __syncthreads();
    if (wave < 2) {
        int s = wave * 2;
        a00 += cb[s][0][lane];  a01 += cb[s][1][lane];  a0d += cb[s][2][lane];
        a10 += cb[s + 1][0][lane];  a11 += cb[s + 1][1][lane];  a1d += cb[s + 1][2][lane];
    }
    __syncthreads();
    // cross-swap: wave0 sends i-tile1 (slot 0), wave1 sends i-tile0 (slot 1)
    if (wave == 0) {
        cb[0][0][lane] = a10;  cb[0][1][lane] = a11;  cb[0][2][lane] = a1d;
    } else if (wave == 1) {
        cb[1][0][lane] = a00;  cb[1][1][lane] = a01;  cb[1][2][lane] = a0d;
    }
    __syncthreads();
    if (wave >= 2) return;
    f32x4 A0, A1, AD;
    if (wave == 0) {
        A0 = a00 + cb[1][0][lane];
        A1 = a01 + cb[1][1][lane];
        AD = a0d + cb[1][2][lane];
    } else {
        A0 = a10 + cb[0][0][lane];
        A1 = a11 + cb[0][1][lane];
        AD = a1d + cb[0][2][lane];
    }

    // epilogue: C/D layout col=lane&15, row=quad*4+reg; AD[r] = denominator
    float* op = out + ((size_t)(b * NSZ) + i0 + wave * 16) * (HH * ODIM) + h * ODIM + col;
#pragma unroll
    for (int r = 0; r < 4; r++) {
        int row = quad * 4 + r;
        float inv = 1.0f / AD[r];
        op[(size_t)row * (HH * ODIM)]      = fmaxf(A0[r] * inv, 0.f);
        op[(size_t)row * (HH * ODIM) + 16] = fmaxf(A1[r] * inv, 0.f);
    }
}

extern "C" void kernel_launch(void* const* d_in, const int* in_sizes, int n_in,
                              void* d_out, int out_size, void* d_ws, size_t ws_size,
                              hipStream_t stream) {
    const float* x     = (const float*)d_in[0];
    const float* adj   = (const float*)d_in[1];
    const float* W     = (const float*)d_in[2];
    const float* a_src = (const float*)d_in[3];
    const float* a_dst = (const float*)d_in[4];
    float* out = (float*)d_out;

    float* ws = (float*)d_ws;
    float* eap            = ws + WS_EAP;
    unsigned short* ebe   = (unsigned short*)(ws + WS_EBP);
    unsigned short* ebe2  = (unsigned short*)(ws + WS_EBP + 65536);
    unsigned* adjb        = (unsigned*)(ws + WS_ADJB);
    int4* whf             = (int4*)(ws + WS_WHF);

    // fused prep: 1024 MFMA-projection blocks first, then 4096 adj blocks
    k_prep<<<dim3(1024 + 4096), dim3(256), 0, stream>>>(x, adj, W, a_src, a_dst,
                                                        adjb, whf, eap, ebe, ebe2);
    // fused masked softmax + MFMA aggregation: 2048 blocks x 4 waves
    k_gat<<<dim3(BB * HH * (NSZ / 32)), dim3(256), 0, stream>>>(whf, eap, ebe, ebe2, adjb, out);
}

// Round 11
// 129.423 us; speedup vs baseline: 1.2610x; 1.0051x over previous
//
#include <hip/hip_runtime.h>
#include <math.h>

#define BB 4
#define NSZ 2048
#define FDIM 128
#define ODIM 32
#define HH 8

typedef short short8 __attribute__((ext_vector_type(8)));
typedef _Float16 half8 __attribute__((ext_vector_type(8)));
typedef float f32x4 __attribute__((ext_vector_type(4)));

// workspace layout (float units)
#define WS_EAP  0                 // float[B*H*N]  R_i = exp(-0.8 a_i)
#define WS_EBP  131072            // f16 EB[B*H*N] + f16 EB2[B*H*N]
#define WS_ADJB 262144            // u32[B*N*64]
#define WS_WHF  786432            // f16 Wh B-frags (4MB)
// whf: int4[((b*H+h)*64 + jt)*2 + ot][64 lanes]

// pack 2 f32 -> 2 f16 (RTZ) in one dword
__device__ __forceinline__ unsigned hpack(float a, float b) {
    unsigned r;
    asm("v_cvt_pkrtz_f16_f32 %0, %1, %2" : "=v"(r) : "v"(a), "v"(b));
    return r;
}

// ---------------------------------------------------------------------------
// Fused prep. Blocks [0,1024): MFMA projection for one (b,h,64 n-rows).
// Blocks [1024,1024+4096): adj bitmask pack, grid-strided 4 chunks/block.
// ---------------------------------------------------------------------------
__global__ __launch_bounds__(256) void k_prep(const float* __restrict__ x,
                                              const float* __restrict__ adj,
                                              const float* __restrict__ W,
                                              const float* __restrict__ a_src,
                                              const float* __restrict__ a_dst,
                                              unsigned* __restrict__ adjb,
                                              int4* __restrict__ whf,
                                              float* __restrict__ eap,
                                              unsigned short* __restrict__ ebe,
                                              unsigned short* __restrict__ ebe2) {
    __shared__ float wsl[FDIM * 33];          // W[h] staged, row-padded (k*33+o)
    __shared__ unsigned short wlds[64][33];   // f16 Wh tile [local n][o], +1 pad
    int t = threadIdx.x;

    if (blockIdx.x >= 1024) {
        // ---------------- adj bitmask part (4 chunks, MLP x4) ----------------
        int bid = blockIdx.x - 1024;
#pragma unroll
        for (int it = 0; it < 4; it++) {
            int g = (it * 4096 + bid) * 256 + t;
            int l = g & 7;
            int word = g >> 3;
            int wk = word & 63;
            int row = word >> 6;
            int i = row & (NSZ - 1);
            const float4 v = *(const float4*)&adj[(size_t)row * NSZ + wk * 32 + l * 4];
            unsigned m = 0;
            if (v.x > 0.f) m |= 1u << (l * 4 + 0);
            if (v.y > 0.f) m |= 1u << (l * 4 + 1);
            if (v.z > 0.f) m |= 1u << (l * 4 + 2);
            if (v.w > 0.f) m |= 1u << (l * 4 + 3);
            m |= (unsigned)__shfl_xor((int)m, 1);
            m |= (unsigned)__shfl_xor((int)m, 2);
            m |= (unsigned)__shfl_xor((int)m, 4);
            if (l == 0) {
                int jb = i - wk * 32;
                if (jb >= 0 && jb < 32) m |= 1u << jb;  // self-loop
                adjb[word] = m;
            }
        }
        return;
    }

    // ---------------- projection part ----------------
    int bidx = blockIdx.x;                      // [0,1024): b(2) h(3) nt(5)
    int b = bidx >> 8;
    int h = (bidx >> 5) & 7;
    int nt = bidx & 31;
    int n0 = nt * 64;
    int w = t >> 6, lane = t & 63;
    int col = lane & 15, quad = lane >> 4;

    // stage W[h] (4096 floats) coalesced into padded LDS
#pragma unroll
    for (int m = 0; m < 16; m++) {
        int idx = t + m * 256;
        wsl[(idx >> 5) * 33 + (idx & 31)] = W[(size_t)h * (FDIM * ODIM) + idx];
    }

    // A-fragments (f16): lane(quad,col) elem j = x[b][n0+w*16+col][kt*32+quad*8+j]
    const float* xp = x + ((size_t)(b * NSZ) + n0 + w * 16 + col) * FDIM + quad * 8;
    int4 afr[4];
#pragma unroll
    for (int kt = 0; kt < 4; kt++) {
        float4 xa = *(const float4*)(xp + kt * 32);
        float4 xb = *(const float4*)(xp + kt * 32 + 4);
        afr[kt] = make_int4((int)hpack(xa.x, xa.y), (int)hpack(xa.z, xa.w),
                            (int)hpack(xb.x, xb.y), (int)hpack(xb.z, xb.w));
    }
    __syncthreads();

    // build W B-frags (f16) from LDS and run 8 MFMAs
    f32x4 alo = {0.f, 0.f, 0.f, 0.f};
    f32x4 ahi = {0.f, 0.f, 0.f, 0.f};
#pragma unroll
    for (int kt = 0; kt < 4; kt++) {
        half8 a8 = __builtin_bit_cast(half8, afr[kt]);
#pragma unroll
        for (int ot = 0; ot < 2; ot++) {
            unsigned d[4];
#pragma unroll
            for (int jp = 0; jp < 4; jp++) {
                float lo = wsl[(kt * 32 + quad * 8 + 2 * jp) * 33 + ot * 16 + col];
                float hi = wsl[(kt * 32 + quad * 8 + 2 * jp + 1) * 33 + ot * 16 + col];
                d[jp] = hpack(lo, hi);
            }
            int4 bf = make_int4((int)d[0], (int)d[1], (int)d[2], (int)d[3]);
            if (ot == 0)
                alo = __builtin_amdgcn_mfma_f32_16x16x32_f16(a8,
                        __builtin_bit_cast(half8, bf), alo, 0, 0, 0);
            else
                ahi = __builtin_amdgcn_mfma_f32_16x16x32_f16(a8,
                        __builtin_bit_cast(half8, bf), ahi, 0, 0, 0);
        }
    }

    // alphas: reduce Wh[row]*a over o (col lanes), then exp factors.
    // R_i = exp(-0.8 pa) (f32); EB/EB2 stored f16 with offset -2 (f16-range-safe).
    float as0 = a_src[h * ODIM + col], as1 = a_src[h * ODIM + 16 + col];
    float ad0 = a_dst[h * ODIM + col], ad1 = a_dst[h * ODIM + 16 + col];
#pragma unroll
    for (int r = 0; r < 4; r++) {
        float pa = alo[r] * as0 + ahi[r] * as1;
        float pb = alo[r] * ad0 + ahi[r] * ad1;
#pragma unroll
        for (int mk = 1; mk <= 8; mk <<= 1) {
            pa += __shfl_xor(pa, mk);
            pb += __shfl_xor(pb, mk);
        }
        if (col == 0) {
            size_t idx = (size_t)(b * HH + h) * NSZ + n0 + w * 16 + quad * 4 + r;
            eap[idx]  = __expf(-0.8f * pa);
            ebe[idx]  = (unsigned short)(hpack(__expf(pb - 2.f), 0.f) & 0xffffu);
            ebe2[idx] = (unsigned short)(hpack(__expf(0.2f * pb - 2.f), 0.f) & 0xffffu);
        }
    }

    // Wh -> LDS (f16), then gather B-fragments: wave w does (jl=w>>1, ot=w&1)
#pragma unroll
    for (int r = 0; r < 4; r++) {
        wlds[w * 16 + quad * 4 + r][col]      = (unsigned short)(hpack(alo[r], 0.f) & 0xffffu);
        wlds[w * 16 + quad * 4 + r][col + 16] = (unsigned short)(hpack(ahi[r], 0.f) & 0xffffu);
    }
    __syncthreads();
    int jl = w >> 1, ot = w & 1;
    unsigned d[4];
#pragma unroll
    for (int jp = 0; jp < 4; jp++) {
        unsigned lo = wlds[jl * 32 + quad * 8 + 2 * jp][ot * 16 + col];
        unsigned hi = wlds[jl * 32 + quad * 8 + 2 * jp + 1][ot * 16 + col];
        d[jp] = (hi << 16) | lo;
    }
    int fragid = ((b * HH + h) * 64 + nt * 2 + jl) * 2 + ot;
    whf[(size_t)fragid * 64 + lane] = make_int4((int)d[0], (int)d[1], (int)d[2], (int)d[3]);
}

// expand mask bits (B, B+1) of w into a dword half-mask:
// bot16 = -bit(B), top16 = -bit(B+1). 3 VALU, no LDS.
template<int B>
__device__ __forceinline__ unsigned mexp2(unsigned w, unsigned selhi) {
    unsigned lo, hi, r;
    asm("v_bfe_i32 %0, %1, %2, 1" : "=v"(lo) : "v"(w), "i"(B));
    asm("v_bfe_i32 %0, %1, %2, 1" : "=v"(hi) : "v"(w), "i"(B + 1));
    asm("v_bfi_b32 %0, %1, %2, %3" : "=v"(r) : "s"(selhi), "v"(hi), "v"(lo));
    return r;
}

// masked q-fragment, f16 packed: q = max(EB, R*EB2) via 4x v_pk_mul_f16 +
// 4x v_pk_max_f16; output dwords ARE the packed f16 A-frag (no cvt needed).
__device__ __forceinline__ int4 pfrag16(unsigned R2, uint4 e, uint4 g,
                                        unsigned w8, unsigned selhi) {
    unsigned r0, r1, r2, r3, q0, q1, q2, q3;
    asm("v_pk_mul_f16 %0, %1, %2" : "=v"(r0) : "v"(R2), "v"(g.x));
    asm("v_pk_mul_f16 %0, %1, %2" : "=v"(r1) : "v"(R2), "v"(g.y));
    asm("v_pk_mul_f16 %0, %1, %2" : "=v"(r2) : "v"(R2), "v"(g.z));
    asm("v_pk_mul_f16 %0, %1, %2" : "=v"(r3) : "v"(R2), "v"(g.w));
    asm("v_pk_max_f16 %0, %1, %2" : "=v"(q0) : "v"(e.x), "v"(r0));
    asm("v_pk_max_f16 %0, %1, %2" : "=v"(q1) : "v"(e.y), "v"(r1));
    asm("v_pk_max_f16 %0, %1, %2" : "=v"(q2) : "v"(e.z), "v"(r2));
    asm("v_pk_max_f16 %0, %1, %2" : "=v"(q3) : "v"(e.w), "v"(r3));
    return make_int4((int)(q0 & mexp2<0>(w8, selhi)),
                     (int)(q1 & mexp2<2>(w8, selhi)),
                     (int)(q2 & mexp2<4>(w8, selhi)),
                     (int)(q3 & mexp2<6>(w8, selhi)));
}

// ---------------------------------------------------------------------------
// Fused masked-softmax aggregation, 8-wave amortized.
// Block = (b,h,64 i-rows): 1024 blocks x 8 waves (512 thr). Wave =
// (i-half ih, jt-quarter jq) -- per-wave structure IDENTICAL to the R10
// winner (24-VGPR acc, f16 loop, 2-i-tile pairing); one 8KB eb staging and
// one prologue now serve 8 waves instead of 4. Combine: two independent
// 4-wave groups, R5 cross-swap scheme, per-group LDS regions (24KB).
// ---------------------------------------------------------------------------
__global__ __launch_bounds__(512) void k_gat(const int4* __restrict__ whf,
                                             const float* __restrict__ eap,
                                             const unsigned short* __restrict__ ebe,
                                             const unsigned short* __restrict__ ebe2,
                                             const unsigned* __restrict__ adjb,
                                             float* __restrict__ out) {
    __shared__ __align__(16) float smem[6144];            // 24KB
    unsigned short* eble = (unsigned short*)smem;         // f16 EB [2048] (4KB)
    unsigned short* eblf = (unsigned short*)smem + 2048;  // f16 EB2[2048] (4KB)

    int t = threadIdx.x;
    int u = blockIdx.x;
    // XCD swizzle: XCD x gets units [x*128,(x+1)*128) = 4 consecutive (b,h)
    int unit = (u & 7) * 128 + (u >> 3);
    int b = unit >> 8;
    int h = (unit >> 5) & 7;
    int i0 = (unit & 31) * 64;
    int wave = t >> 6, lane = t & 63;
    int ih = wave >> 2, jq = wave & 3;
    int col = lane & 15, quad = lane >> 4, qsh = quad * 8;
    size_t bh = (size_t)(b * HH + h);
    const unsigned selhi = 0xFFFF0000u;

    // stage f16 EB/EB2 tables: 8KB total, one float4 per thread
    const float4* ege = (const float4*)(ebe + bh * NSZ);
    const float4* egf = (const float4*)(ebe2 + bh * NSZ);
    if (t < 256) ((float4*)eble)[t] = ege[t];
    else         ((float4*)eblf)[t - 256] = egf[t - 256];

    // row factors for this wave's two i-tiles: rows iw+col, iw+16+col
    int iw = i0 + ih * 32;
    float Ra = eap[bh * NSZ + iw + col];
    float Rb = eap[bh * NSZ + iw + 16 + col];
    unsigned R20 = hpack(Ra, Ra);
    unsigned R21 = hpack(Rb, Rb);
    // mask base: row (iw+tt*16+col), words [jq*16 .. jq*16+16)
    const char* mbase = (const char*)(adjb + ((size_t)(b * NSZ) + iw + col) * 64)
                        + (size_t)jq * 64;
    const int4* bfp = whf + bh * 8192 + (size_t)(jq * 16) * 128 + lane;

    f32x4 a00 = {0.f,0.f,0.f,0.f}, a01 = {0.f,0.f,0.f,0.f}, a0d = {0.f,0.f,0.f,0.f};
    f32x4 a10 = {0.f,0.f,0.f,0.f}, a11 = {0.f,0.f,0.f,0.f}, a1d = {0.f,0.f,0.f,0.f};
    const int4 onesv = make_int4(0x3C003C00, 0x3C003C00, 0x3C003C00, 0x3C003C00);
    half8 hones = __builtin_bit_cast(half8, onesv);

    __syncthreads();

    for (int g = 0; g < 4; g++) {
        // batched load phase: 10 independent global loads in flight
        uint4 m0 = *(const uint4*)(mbase + 0 * 4096 + g * 16);
        uint4 m1 = *(const uint4*)(mbase + 1 * 4096 + g * 16);
        int4 blo[4], bhi[4];
#pragma unroll
        for (int q = 0; q < 4; q++) {
            blo[q] = bfp[(g * 4 + q) * 128];
            bhi[q] = bfp[(g * 4 + q) * 128 + 64];
        }
        unsigned ma0[4] = {m0.x, m0.y, m0.z, m0.w};
        unsigned ma1[4] = {m1.x, m1.y, m1.z, m1.w};
#pragma unroll
        for (int q = 0; q < 4; q++) {
            int jt = jq * 16 + g * 4 + q;
            uint4 ef = *(const uint4*)&eble[jt * 32 + qsh];   // 8 f16 EB
            uint4 gf = *(const uint4*)&eblf[jt * 32 + qsh];   // 8 f16 EB2
            half8 b0 = __builtin_bit_cast(half8, blo[q]);
            half8 b1 = __builtin_bit_cast(half8, bhi[q]);
            int4 f0 = pfrag16(R20, ef, gf, ma0[q] >> qsh, selhi);
            int4 f1 = pfrag16(R21, ef, gf, ma1[q] >> qsh, selhi);
            half8 af0 = __builtin_bit_cast(half8, f0);
            half8 af1 = __builtin_bit_cast(half8, f1);
            a00 = __builtin_amdgcn_mfma_f32_16x16x32_f16(af0, b0, a00, 0, 0, 0);
            a01 = __builtin_amdgcn_mfma_f32_16x16x32_f16(af0, b1, a01, 0, 0, 0);
            a0d = __builtin_amdgcn_mfma_f32_16x16x32_f16(af0, hones, a0d, 0, 0, 0);
            a10 = __builtin_amdgcn_mfma_f32_16x16x32_f16(af1, b0, a10, 0, 0, 0);
            a11 = __builtin_amdgcn_mfma_f32_16x16x32_f16(af1, b1, a11, 0, 0, 0);
            a1d = __builtin_amdgcn_mfma_f32_16x16x32_f16(af1, hones, a1d, 0, 0, 0);
        }
    }

    // tree combine, two independent 4-wave groups (slots: group ih -> ih*4+..)
    f32x4 (*cb)[3][64] = (f32x4 (*)[3][64])smem;   // 8 slots x 3KB = 24KB
    __syncthreads();                 // eb reads done; buffer dead
    if (jq >= 2) {
        int s = ih * 4 + (jq - 2) * 2;
        cb[s][0][lane] = a00;  cb[s][1][lane] = a01;  cb[s][2][lane] = a0d;
        cb[s + 1][0][lane] = a10;  cb[s + 1][1][lane] = a11;  cb[s + 1][2][lane] = a1d;
    }
    __syncthreads();
    if (jq < 2) {
        int s = ih * 4 + jq * 2;
        a00 += cb[s][0][lane];  a01 += cb[s][1][lane];  a0d += cb[s][2][lane];
        a10 += cb[s + 1][0][lane];  a11 += cb[s + 1][1][lane];  a1d += cb[s + 1][2][lane];
    }
    __syncthreads();
    // cross-swap: jq0 sends i-tile1 (slot ih*4), jq1 sends i-tile0 (slot ih*4+1)
    if (jq == 0) {
        int s = ih * 4;
        cb[s][0][lane] = a10;  cb[s][1][lane] = a11;  cb[s][2][lane] = a1d;
    } else if (jq == 1) {
        int s = ih * 4 + 1;
        cb[s][0][lane] = a00;  cb[s][1][lane] = a01;  cb[s][2][lane] = a0d;
    }
    __syncthreads();
    if (jq >= 2) return;
    f32x4 A0, A1, AD;
    if (jq == 0) {
        int s = ih * 4 + 1;
        A0 = a00 + cb[s][0][lane];
        A1 = a01 + cb[s][1][lane];
        AD = a0d + cb[s][2][lane];
    } else {
        int s = ih * 4;
        A0 = a10 + cb[s][0][lane];
        A1 = a11 + cb[s][1][lane];
        AD = a1d + cb[s][2][lane];
    }

    // epilogue: C/D layout col=lane&15, row=quad*4+reg; AD[r] = denominator
    float* op = out + ((size_t)(b * NSZ) + iw + jq * 16) * (HH * ODIM) + h * ODIM + col;
#pragma unroll
    for (int r = 0; r < 4; r++) {
        int row = quad * 4 + r;
        float inv = 1.0f / AD[r];
        op[(size_t)row * (HH * ODIM)]      = fmaxf(A0[r] * inv, 0.f);
        op[(size_t)row * (HH * ODIM) + 16] = fmaxf(A1[r] * inv, 0.f);
    }
}

extern "C" void kernel_launch(void* const* d_in, const int* in_sizes, int n_in,
                              void* d_out, int out_size, void* d_ws, size_t ws_size,
                              hipStream_t stream) {
    const float* x     = (const float*)d_in[0];
    const float* adj   = (const float*)d_in[1];
    const float* W     = (const float*)d_in[2];
    const float* a_src = (const float*)d_in[3];
    const float* a_dst = (const float*)d_in[4];
    float* out = (float*)d_out;

    float* ws = (float*)d_ws;
    float* eap            = ws + WS_EAP;
    unsigned short* ebe   = (unsigned short*)(ws + WS_EBP);
    unsigned short* ebe2  = (unsigned short*)(ws + WS_EBP + 65536);
    unsigned* adjb        = (unsigned*)(ws + WS_ADJB);
    int4* whf             = (int4*)(ws + WS_WHF);

    // fused prep: 1024 MFMA-projection blocks first, then 4096 adj blocks
    k_prep<<<dim3(1024 + 4096), dim3(256), 0, stream>>>(x, adj, W, a_src, a_dst,
                                                        adjb, whf, eap, ebe, ebe2);
    // fused masked softmax + MFMA aggregation: 1024 blocks x 8 waves
    k_gat<<<dim3(BB * HH * (NSZ / 64)), dim3(512), 0, stream>>>(whf, eap, ebe, ebe2, adjb, out);
}

// Round 12
// 129.312 us; speedup vs baseline: 1.2621x; 1.0009x over previous
//
#include <hip/hip_runtime.h>
#include <math.h>

#define BB 4
#define NSZ 2048
#define FDIM 128
#define ODIM 32
#define HH 8

typedef short short8 __attribute__((ext_vector_type(8)));
typedef _Float16 half8 __attribute__((ext_vector_type(8)));
typedef float f32x4 __attribute__((ext_vector_type(4)));

// workspace layout (float units)
#define WS_EAP  0                 // float[B*H*N]  R_i = exp(-0.8 a_i)
#define WS_EBP  131072            // f16 EB[B*H*N] + f16 EB2[B*H*N]
#define WS_ADJB 262144            // u32[B*N*64]
#define WS_WHF  786432            // f16 Wh B-frags (4MB)
// whf: int4[((b*H+h)*64 + jt)*2 + ot][64 lanes]

// pack 2 f32 -> 2 f16 (RTZ) in one dword
__device__ __forceinline__ unsigned hpack(float a, float b) {
    unsigned r;
    asm("v_cvt_pkrtz_f16_f32 %0, %1, %2" : "=v"(r) : "v"(a), "v"(b));
    return r;
}

// ---------------------------------------------------------------------------
// Fused prep. Blocks [0,1024): MFMA projection for one (b,h,64 n-rows).
// Blocks [1024,1024+4096): adj bitmask pack, grid-strided 4 chunks/block.
// ---------------------------------------------------------------------------
__global__ __launch_bounds__(256) void k_prep(const float* __restrict__ x,
                                              const float* __restrict__ adj,
                                              const float* __restrict__ W,
                                              const float* __restrict__ a_src,
                                              const float* __restrict__ a_dst,
                                              unsigned* __restrict__ adjb,
                                              int4* __restrict__ whf,
                                              float* __restrict__ eap,
                                              unsigned short* __restrict__ ebe,
                                              unsigned short* __restrict__ ebe2) {
    __shared__ float wsl[FDIM * 33];          // W[h] staged, row-padded (k*33+o)
    __shared__ unsigned short wlds[64][33];   // f16 Wh tile [local n][o], +1 pad
    int t = threadIdx.x;

    if (blockIdx.x >= 1024) {
        // ---------------- adj bitmask part (4 chunks, MLP x4) ----------------
        int bid = blockIdx.x - 1024;
#pragma unroll
        for (int it = 0; it < 4; it++) {
            int g = (it * 4096 + bid) * 256 + t;
            int l = g & 7;
            int word = g >> 3;
            int wk = word & 63;
            int row = word >> 6;
            int i = row & (NSZ - 1);
            const float4 v = *(const float4*)&adj[(size_t)row * NSZ + wk * 32 + l * 4];
            unsigned m = 0;
            if (v.x > 0.f) m |= 1u << (l * 4 + 0);
            if (v.y > 0.f) m |= 1u << (l * 4 + 1);
            if (v.z > 0.f) m |= 1u << (l * 4 + 2);
            if (v.w > 0.f) m |= 1u << (l * 4 + 3);
            m |= (unsigned)__shfl_xor((int)m, 1);
            m |= (unsigned)__shfl_xor((int)m, 2);
            m |= (unsigned)__shfl_xor((int)m, 4);
            if (l == 0) {
                int jb = i - wk * 32;
                if (jb >= 0 && jb < 32) m |= 1u << jb;  // self-loop
                adjb[word] = m;
            }
        }
        return;
    }

    // ---------------- projection part ----------------
    int bidx = blockIdx.x;                      // [0,1024): b(2) h(3) nt(5)
    int b = bidx >> 8;
    int h = (bidx >> 5) & 7;
    int nt = bidx & 31;
    int n0 = nt * 64;
    int w = t >> 6, lane = t & 63;
    int col = lane & 15, quad = lane >> 4;

    // stage W[h] (4096 floats) coalesced into padded LDS
#pragma unroll
    for (int m = 0; m < 16; m++) {
        int idx = t + m * 256;
        wsl[(idx >> 5) * 33 + (idx & 31)] = W[(size_t)h * (FDIM * ODIM) + idx];
    }

    // A-fragments (f16): lane(quad,col) elem j = x[b][n0+w*16+col][kt*32+quad*8+j]
    const float* xp = x + ((size_t)(b * NSZ) + n0 + w * 16 + col) * FDIM + quad * 8;
    int4 afr[4];
#pragma unroll
    for (int kt = 0; kt < 4; kt++) {
        float4 xa = *(const float4*)(xp + kt * 32);
        float4 xb = *(const float4*)(xp + kt * 32 + 4);
        afr[kt] = make_int4((int)hpack(xa.x, xa.y), (int)hpack(xa.z, xa.w),
                            (int)hpack(xb.x, xb.y), (int)hpack(xb.z, xb.w));
    }
    __syncthreads();

    // build W B-frags (f16) from LDS and run 8 MFMAs
    f32x4 alo = {0.f, 0.f, 0.f, 0.f};
    f32x4 ahi = {0.f, 0.f, 0.f, 0.f};
#pragma unroll
    for (int kt = 0; kt < 4; kt++) {
        half8 a8 = __builtin_bit_cast(half8, afr[kt]);
#pragma unroll
        for (int ot = 0; ot < 2; ot++) {
            unsigned d[4];
#pragma unroll
            for (int jp = 0; jp < 4; jp++) {
                float lo = wsl[(kt * 32 + quad * 8 + 2 * jp) * 33 + ot * 16 + col];
                float hi = wsl[(kt * 32 + quad * 8 + 2 * jp + 1) * 33 + ot * 16 + col];
                d[jp] = hpack(lo, hi);
            }
            int4 bf = make_int4((int)d[0], (int)d[1], (int)d[2], (int)d[3]);
            if (ot == 0)
                alo = __builtin_amdgcn_mfma_f32_16x16x32_f16(a8,
                        __builtin_bit_cast(half8, bf), alo, 0, 0, 0);
            else
                ahi = __builtin_amdgcn_mfma_f32_16x16x32_f16(a8,
                        __builtin_bit_cast(half8, bf), ahi, 0, 0, 0);
        }
    }

    // alphas: reduce Wh[row]*a over o (col lanes), then exp factors.
    // R_i = exp(-0.8 pa) (f32); EB/EB2 stored f16 with offset -2 (f16-range-safe).
    float as0 = a_src[h * ODIM + col], as1 = a_src[h * ODIM + 16 + col];
    float ad0 = a_dst[h * ODIM + col], ad1 = a_dst[h * ODIM + 16 + col];
#pragma unroll
    for (int r = 0; r < 4; r++) {
        float pa = alo[r] * as0 + ahi[r] * as1;
        float pb = alo[r] * ad0 + ahi[r] * ad1;
#pragma unroll
        for (int mk = 1; mk <= 8; mk <<= 1) {
            pa += __shfl_xor(pa, mk);
            pb += __shfl_xor(pb, mk);
        }
        if (col == 0) {
            size_t idx = (size_t)(b * HH + h) * NSZ + n0 + w * 16 + quad * 4 + r;
            eap[idx]  = __expf(-0.8f * pa);
            ebe[idx]  = (unsigned short)(hpack(__expf(pb - 2.f), 0.f) & 0xffffu);
            ebe2[idx] = (unsigned short)(hpack(__expf(0.2f * pb - 2.f), 0.f) & 0xffffu);
        }
    }

    // Wh -> LDS (f16), then gather B-fragments: wave w does (jl=w>>1, ot=w&1)
#pragma unroll
    for (int r = 0; r < 4; r++) {
        wlds[w * 16 + quad * 4 + r][col]      = (unsigned short)(hpack(alo[r], 0.f) & 0xffffu);
        wlds[w * 16 + quad * 4 + r][col + 16] = (unsigned short)(hpack(ahi[r], 0.f) & 0xffffu);
    }
    __syncthreads();
    int jl = w >> 1, ot = w & 1;
    unsigned d[4];
#pragma unroll
    for (int jp = 0; jp < 4; jp++) {
        unsigned lo = wlds[jl * 32 + quad * 8 + 2 * jp][ot * 16 + col];
        unsigned hi = wlds[jl * 32 + quad * 8 + 2 * jp + 1][ot * 16 + col];
        d[jp] = (hi << 16) | lo;
    }
    int fragid = ((b * HH + h) * 64 + nt * 2 + jl) * 2 + ot;
    whf[(size_t)fragid * 64 + lane] = make_int4((int)d[0], (int)d[1], (int)d[2], (int)d[3]);
}

// masked q-fragment, f16 packed: q = max(EB, R*EB2) via 4x v_pk_mul_f16 +
// 4x v_pk_max_f16. Mask applied via 16-entry LDS LUT (4 bits -> 2 AND-mask
// dwords): 2x ds_read_b64 + 4 AND per pfrag -- moves ~12 VALU onto the
// slack LDS pipe (R0 measured this LUT pattern conflict-free: same-entry
// lanes broadcast, distinct entries hit distinct bank pairs).
__device__ __forceinline__ int4 pfrag16(unsigned R2, uint4 e, uint4 g,
                                        unsigned w8,
                                        const unsigned (*__restrict__ mlut)[2]) {
    unsigned r0, r1, r2, r3, q0, q1, q2, q3;
    asm("v_pk_mul_f16 %0, %1, %2" : "=v"(r0) : "v"(R2), "v"(g.x));
    asm("v_pk_mul_f16 %0, %1, %2" : "=v"(r1) : "v"(R2), "v"(g.y));
    asm("v_pk_mul_f16 %0, %1, %2" : "=v"(r2) : "v"(R2), "v"(g.z));
    asm("v_pk_mul_f16 %0, %1, %2" : "=v"(r3) : "v"(R2), "v"(g.w));
    asm("v_pk_max_f16 %0, %1, %2" : "=v"(q0) : "v"(e.x), "v"(r0));
    asm("v_pk_max_f16 %0, %1, %2" : "=v"(q1) : "v"(e.y), "v"(r1));
    asm("v_pk_max_f16 %0, %1, %2" : "=v"(q2) : "v"(e.z), "v"(r2));
    asm("v_pk_max_f16 %0, %1, %2" : "=v"(q3) : "v"(e.w), "v"(r3));
    const unsigned* mA = mlut[w8 & 15];         // bits 0..3 -> masks dw0,dw1
    const unsigned* mB = mlut[(w8 >> 4) & 15];  // bits 4..7 -> masks dw2,dw3
    return make_int4((int)(q0 & mA[0]), (int)(q1 & mA[1]),
                     (int)(q2 & mB[0]), (int)(q3 & mB[1]));
}

// ---------------------------------------------------------------------------
// Fused masked-softmax aggregation, 8-wave amortized, LDS-LUT masks.
// Block = (b,h,64 i-rows): 1024 blocks x 8 waves (512 thr). Wave =
// (i-half ih, jt-quarter jq); f16 loop (R9) + LUT mask offload (this round).
// launch_bounds(512,4): VGPR <= 128 (insurance vs occupancy cliff; kernel
// needs ~95-110 so no spill). Combine: two independent 4-wave groups, R5
// cross-swap scheme (24KB, overlays eb+mlut after the loop).
// ---------------------------------------------------------------------------
__global__ __launch_bounds__(512, 4) void k_gat(const int4* __restrict__ whf,
                                                const float* __restrict__ eap,
                                                const unsigned short* __restrict__ ebe,
                                                const unsigned short* __restrict__ ebe2,
                                                const unsigned* __restrict__ adjb,
                                                float* __restrict__ out) {
    __shared__ __align__(16) float smem[6144];            // 24KB
    unsigned short* eble = (unsigned short*)smem;         // f16 EB [2048] (4KB)
    unsigned short* eblf = (unsigned short*)smem + 2048;  // f16 EB2[2048] (4KB)
    unsigned (*mlut)[2] = (unsigned (*)[2])(smem + 2048); // 128B at offset 8KB

    int t = threadIdx.x;
    int u = blockIdx.x;
    // XCD swizzle: XCD x gets units [x*128,(x+1)*128) = 4 consecutive (b,h)
    int unit = (u & 7) * 128 + (u >> 3);
    int b = unit >> 8;
    int h = (unit >> 5) & 7;
    int i0 = (unit & 31) * 64;
    int wave = t >> 6, lane = t & 63;
    int ih = wave >> 2, jq = wave & 3;
    int col = lane & 15, quad = lane >> 4, qsh = quad * 8;
    size_t bh = (size_t)(b * HH + h);

    // mask LUT: 4 bits -> 2 dwords of 16-bit AND-masks
    if (t < 16) {
        mlut[t][0] = ((t & 1) ? 0x0000FFFFu : 0u) | ((t & 2) ? 0xFFFF0000u : 0u);
        mlut[t][1] = ((t & 4) ? 0x0000FFFFu : 0u) | ((t & 8) ? 0xFFFF0000u : 0u);
    }

    // stage f16 EB/EB2 tables: 8KB total, one float4 per thread
    const float4* ege = (const float4*)(ebe + bh * NSZ);
    const float4* egf = (const float4*)(ebe2 + bh * NSZ);
    if (t < 256) ((float4*)eble)[t] = ege[t];
    else         ((float4*)eblf)[t - 256] = egf[t - 256];

    // row factors for this wave's two i-tiles: rows iw+col, iw+16+col
    int iw = i0 + ih * 32;
    float Ra = eap[bh * NSZ + iw + col];
    float Rb = eap[bh * NSZ + iw + 16 + col];
    unsigned R20 = hpack(Ra, Ra);
    unsigned R21 = hpack(Rb, Rb);
    // mask base: row (iw+tt*16+col), words [jq*16 .. jq*16+16)
    const char* mbase = (const char*)(adjb + ((size_t)(b * NSZ) + iw + col) * 64)
                        + (size_t)jq * 64;
    const int4* bfp = whf + bh * 8192 + (size_t)(jq * 16) * 128 + lane;

    f32x4 a00 = {0.f,0.f,0.f,0.f}, a01 = {0.f,0.f,0.f,0.f}, a0d = {0.f,0.f,0.f,0.f};
    f32x4 a10 = {0.f,0.f,0.f,0.f}, a11 = {0.f,0.f,0.f,0.f}, a1d = {0.f,0.f,0.f,0.f};
    const int4 onesv = make_int4(0x3C003C00, 0x3C003C00, 0x3C003C00, 0x3C003C00);
    half8 hones = __builtin_bit_cast(half8, onesv);

    __syncthreads();

    for (int g = 0; g < 4; g++) {
        // batched load phase: 10 independent global loads in flight
        uint4 m0 = *(const uint4*)(mbase + 0 * 4096 + g * 16);
        uint4 m1 = *(const uint4*)(mbase + 1 * 4096 + g * 16);
        int4 blo[4], bhi[4];
#pragma unroll
        for (int q = 0; q < 4; q++) {
            blo[q] = bfp[(g * 4 + q) * 128];
            bhi[q] = bfp[(g * 4 + q) * 128 + 64];
        }
        unsigned ma0[4] = {m0.x, m0.y, m0.z, m0.w};
        unsigned ma1[4] = {m1.x, m1.y, m1.z, m1.w};
#pragma unroll
        for (int q = 0; q < 4; q++) {
            int jt = jq * 16 + g * 4 + q;
            uint4 ef = *(const uint4*)&eble[jt * 32 + qsh];   // 8 f16 EB
            uint4 gf = *(const uint4*)&eblf[jt * 32 + qsh];   // 8 f16 EB2
            half8 b0 = __builtin_bit_cast(half8, blo[q]);
            half8 b1 = __builtin_bit_cast(half8, bhi[q]);
            int4 f0 = pfrag16(R20, ef, gf, ma0[q] >> qsh, mlut);
            int4 f1 = pfrag16(R21, ef, gf, ma1[q] >> qsh, mlut);
            half8 af0 = __builtin_bit_cast(half8, f0);
            half8 af1 = __builtin_bit_cast(half8, f1);
            a00 = __builtin_amdgcn_mfma_f32_16x16x32_f16(af0, b0, a00, 0, 0, 0);
            a01 = __builtin_amdgcn_mfma_f32_16x16x32_f16(af0, b1, a01, 0, 0, 0);
            a0d = __builtin_amdgcn_mfma_f32_16x16x32_f16(af0, hones, a0d, 0, 0, 0);
            a10 = __builtin_amdgcn_mfma_f32_16x16x32_f16(af1, b0, a10, 0, 0, 0);
            a11 = __builtin_amdgcn_mfma_f32_16x16x32_f16(af1, b1, a11, 0, 0, 0);
            a1d = __builtin_amdgcn_mfma_f32_16x16x32_f16(af1, hones, a1d, 0, 0, 0);
        }
    }

    // tree combine, two independent 4-wave groups (slots: group ih -> ih*4+..)
    f32x4 (*cb)[3][64] = (f32x4 (*)[3][64])smem;   // 8 slots x 3KB = 24KB
    __syncthreads();                 // eb+mlut reads done; buffers dead
    if (jq >= 2) {
        int s = ih * 4 + (jq - 2) * 2;
        cb[s][0][lane] = a00;  cb[s][1][lane] = a01;  cb[s][2][lane] = a0d;
        cb[s + 1][0][lane] = a10;  cb[s + 1][1][lane] = a11;  cb[s + 1][2][lane] = a1d;
    }
    __syncthreads();
    if (jq < 2) {
        int s = ih * 4 + jq * 2;
        a00 += cb[s][0][lane];  a01 += cb[s][1][lane];  a0d += cb[s][2][lane];
        a10 += cb[s + 1][0][lane];  a11 += cb[s + 1][1][lane];  a1d += cb[s + 1][2][lane];
    }
    __syncthreads();
    // cross-swap: jq0 sends i-tile1 (slot ih*4), jq1 sends i-tile0 (slot ih*4+1)
    if (jq == 0) {
        int s = ih * 4;
        cb[s][0][lane] = a10;  cb[s][1][lane] = a11;  cb[s][2][lane] = a1d;
    } else if (jq == 1) {
        int s = ih * 4 + 1;
        cb[s][0][lane] = a00;  cb[s][1][lane] = a01;  cb[s][2][lane] = a0d;
    }
    __syncthreads();
    if (jq >= 2) return;
    f32x4 A0, A1, AD;
    if (jq == 0) {
        int s = ih * 4 + 1;
        A0 = a00 + cb[s][0][lane];
        A1 = a01 + cb[s][1][lane];
        AD = a0d + cb[s][2][lane];
    } else {
        int s = ih * 4;
        A0 = a10 + cb[s][0][lane];
        A1 = a11 + cb[s][1][lane];
        AD = a1d + cb[s][2][lane];
    }

    // epilogue: C/D layout col=lane&15, row=quad*4+reg; AD[r] = denominator
    float* op = out + ((size_t)(b * NSZ) + iw + jq * 16) * (HH * ODIM) + h * ODIM + col;
#pragma unroll
    for (int r = 0; r < 4; r++) {
        int row = quad * 4 + r;
        float inv = 1.0f / AD[r];
        op[(size_t)row * (HH * ODIM)]      = fmaxf(A0[r] * inv, 0.f);
        op[(size_t)row * (HH * ODIM) + 16] = fmaxf(A1[r] * inv, 0.f);
    }
}

extern "C" void kernel_launch(void* const* d_in, const int* in_sizes, int n_in,
                              void* d_out, int out_size, void* d_ws, size_t ws_size,
                              hipStream_t stream) {
    const float* x     = (const float*)d_in[0];
    const float* adj   = (const float*)d_in[1];
    const float* W     = (const float*)d_in[2];
    const float* a_src = (const float*)d_in[3];
    const float* a_dst = (const float*)d_in[4];
    float* out = (float*)d_out;

    float* ws = (float*)d_ws;
    float* eap            = ws + WS_EAP;
    unsigned short* ebe   = (unsigned short*)(ws + WS_EBP);
    unsigned short* ebe2  = (unsigned short*)(ws + WS_EBP + 65536);
    unsigned* adjb        = (unsigned*)(ws + WS_ADJB);
    int4* whf             = (int4*)(ws + WS_WHF);

    // fused prep: 1024 MFMA-projection blocks first, then 4096 adj blocks
    k_prep<<<dim3(1024 + 4096), dim3(256), 0, stream>>>(x, adj, W, a_src, a_dst,
                                                        adjb, whf, eap, ebe, ebe2);
    // fused masked softmax + MFMA aggregation: 1024 blocks x 8 waves
    k_gat<<<dim3(BB * HH * (NSZ / 64)), dim3(512), 0, stream>>>(whf, eap, ebe, ebe2, adjb, out);
}